// Round 1
// baseline (5847.723 us; speedup 1.0000x reference)
//
#include <hip/hip_runtime.h>
#include <math.h>

__device__ __forceinline__ float sigmoidf_(float x) { return 1.0f / (1.0f + __expf(-x)); }

// ---------- dense 32-in/32-out linear: out = [relu?](X) @ W^T + b ----------
template<bool RELU_IN>
__global__ __launch_bounds__(256) void lin32_kernel(
    const float* __restrict__ X, const float* __restrict__ W,
    const float* __restrict__ b, float* __restrict__ out, int N)
{
  __shared__ float sW[32][33];
  __shared__ float sb[32];
  __shared__ float sX[8][33];
  const int tid = threadIdx.x;
  for (int i = tid; i < 1024; i += 256) sW[i >> 5][i & 31] = W[i];
  if (tid < 32) sb[tid] = b[tid];
  const int n0 = blockIdx.x * 8;
  {
    float v = X[(size_t)n0 * 32 + tid];
    if (RELU_IN) v = fmaxf(v, 0.0f);
    sX[tid >> 5][tid & 31] = v;
  }
  __syncthreads();
  const int ln = tid >> 5, f = tid & 31;
  float acc = sb[f];
  #pragma unroll
  for (int j = 0; j < 32; j++) acc += sX[ln][j] * sW[f][j];
  out[(size_t)n0 * 32 + tid] = acc;
}

// ---------- SpMM: out[row[e]] += val[e] * X[col[e]]  (32 feats, atomics) ----------
__global__ __launch_bounds__(256) void spmm_kernel(
    const int* __restrict__ erow, const int* __restrict__ ecol,
    const float* __restrict__ eval, const float* __restrict__ X,
    float* __restrict__ out, int E)
{
  const long gid = (long)blockIdx.x * 256 + threadIdx.x;
  const int e = (int)(gid >> 3);
  const int q = (int)(gid & 7);
  if (e >= E) return;
  const int r = erow[e], c = ecol[e];
  const float v = eval[e];
  const float4 x = *(const float4*)(X + (size_t)c * 32 + q * 4);
  float* o = out + (size_t)r * 32 + q * 4;
  atomicAdd(o + 0, v * x.x);
  atomicAdd(o + 1, v * x.y);
  atomicAdd(o + 2, v * x.z);
  atomicAdd(o + 3, v * x.w);
}

// ---------- fused GRU (T steps) + MLP head, 32 nodes per block ----------
#define NB 32

__global__ __launch_bounds__(256, 2) void gru_head_kernel(
    const float* __restrict__ acc2,   // (N,32) pre-relu graph output
    const float* __restrict__ xdyn,   // (T,N,8)
    const float* __restrict__ Wih,    // (192,40) [r,z,n] x [h(32), xd(8)]
    const float* __restrict__ Whh,    // (192,64)
    const float* __restrict__ bih, const float* __restrict__ bhh,
    const float* __restrict__ h1Wg,   // (64,64)
    const float* __restrict__ h1bg,   // (64)
    const float* __restrict__ h2Wg,   // (64)
    const float* __restrict__ h2bg,   // (1)
    float* __restrict__ out, int N, int T)
{
  __shared__ float s_h[64][NB];     // GRU state, [j][node]
  __shared__ float s_A[NB][193];    // staging: [node][k]  (k<128: i+h; k>=128: i_n)
  __shared__ float s_B[NB][65];     // staging: h_n
  __shared__ float s_xd[8][NB];     // dyn features, [f][node]
  __shared__ float s_hg[NB][32];    // relu(graph h), [node][f]
  __shared__ float s_h1W[64][67];   // head weights, padded

  const int tid = threadIdx.x;
  const int n0 = blockIdx.x * NB;

  for (int i = tid; i < NB * 32; i += 256)
    s_hg[i >> 5][i & 31] = fmaxf(acc2[(size_t)n0 * 32 + i], 0.0f);
  for (int i = tid; i < 64 * 64; i += 256)
    s_h1W[i >> 6][i & 63] = h1Wg[i];
  for (int i = tid; i < 64 * NB; i += 256)
    (&s_h[0][0])[i] = 0.0f;
  __syncthreads();

  const int k = tid;                 // gate-row role (tid < 192)
  const int o = tid & 63;            // head-output role
  const int hn0 = (tid >> 6) * 8;    // 8 nodes per thread in head phase

  float w_hh[64], w_id[8], gis[NB];
  float bhh_k = 0.0f;
  if (k < 192) {
    #pragma unroll
    for (int j = 0; j < 64; j++) w_hh[j] = Whh[k * 64 + j];
    #pragma unroll
    for (int f = 0; f < 8; f++) w_id[f] = Wih[k * 40 + 32 + f];
    bhh_k = bhh[k];
    float w_is[32];
    #pragma unroll
    for (int f = 0; f < 32; f++) w_is[f] = Wih[k * 40 + f];
    const float bik = bih[k];
    #pragma unroll
    for (int n = 0; n < NB; n++) {
      float a = bik;
      #pragma unroll
      for (int f = 0; f < 8; f++) {
        const float4 x = *(const float4*)&s_hg[n][4 * f];
        a += w_is[4*f] * x.x + w_is[4*f+1] * x.y + w_is[4*f+2] * x.z + w_is[4*f+3] * x.w;
      }
      gis[n] = a;
    }
  }
  const float h1b_o = h1bg[o];
  const float h2w_o = h2Wg[o];
  const float h2b_s = h2bg[0];

  for (int t = 0; t < T; t++) {
    // P0: stage this step's dynamic features (transposed)
    if (tid < 64) {
      const float4 v = *(const float4*)(xdyn + ((size_t)t * N + n0) * 8 + tid * 4);
      const int i = tid * 4;
      const int nd = i >> 3, f0 = i & 7;
      s_xd[f0 + 0][nd] = v.x;
      s_xd[f0 + 1][nd] = v.y;
      s_xd[f0 + 2][nd] = v.z;
      s_xd[f0 + 3][nd] = v.w;
    }
    __syncthreads();

    // P1: gate pre-activations, thread k owns gate-row k; W_hh row in registers
    if (k < 192) {
      #pragma unroll
      for (int g = 0; g < 8; g++) {
        const int nb = 4 * g;
        float ai0 = gis[nb], ai1 = gis[nb+1], ai2 = gis[nb+2], ai3 = gis[nb+3];
        #pragma unroll
        for (int f = 0; f < 8; f++) {
          const float4 x = *(const float4*)&s_xd[f][nb];
          ai0 += w_id[f] * x.x; ai1 += w_id[f] * x.y;
          ai2 += w_id[f] * x.z; ai3 += w_id[f] * x.w;
        }
        float ah0 = bhh_k, ah1 = bhh_k, ah2 = bhh_k, ah3 = bhh_k;
        #pragma unroll
        for (int j = 0; j < 64; j++) {
          const float4 h = *(const float4*)&s_h[j][nb];
          ah0 += w_hh[j] * h.x; ah1 += w_hh[j] * h.y;
          ah2 += w_hh[j] * h.z; ah3 += w_hh[j] * h.w;
        }
        if (k < 128) {
          s_A[nb+0][k] = ai0 + ah0; s_A[nb+1][k] = ai1 + ah1;
          s_A[nb+2][k] = ai2 + ah2; s_A[nb+3][k] = ai3 + ah3;
        } else {
          s_A[nb+0][k] = ai0; s_A[nb+1][k] = ai1;
          s_A[nb+2][k] = ai2; s_A[nb+3][k] = ai3;
          s_B[nb+0][k-128] = ah0; s_B[nb+1][k-128] = ah1;
          s_B[nb+2][k-128] = ah2; s_B[nb+3][k-128] = ah3;
        }
      }
    }
    __syncthreads();

    // P2: gate nonlinearities + state update
    {
      const int n = tid & 31, j0 = (tid >> 5) * 8;
      #pragma unroll
      for (int jj = 0; jj < 8; jj++) {
        const int j = j0 + jj;
        const float r  = sigmoidf_(s_A[n][j]);
        const float z  = sigmoidf_(s_A[n][64 + j]);
        const float nn = tanhf(s_A[n][128 + j] + r * s_B[n][j]);
        const float hp = s_h[j][n];
        s_h[j][n] = (1.0f - z) * nn + z * hp;
      }
    }
    __syncthreads();

    // P3: head  y = sigmoid(h2W . relu(h1W @ h + h1b) + h2b)
    {
      float red[8];
      #pragma unroll
      for (int g = 0; g < 2; g++) {
        const int nb = hn0 + 4 * g;
        float a0 = h1b_o, a1 = h1b_o, a2 = h1b_o, a3 = h1b_o;
        #pragma unroll 8
        for (int j = 0; j < 64; j++) {
          const float w = s_h1W[o][j];
          const float4 h = *(const float4*)&s_h[j][nb];
          a0 += w * h.x; a1 += w * h.y; a2 += w * h.z; a3 += w * h.w;
        }
        red[4*g+0] = h2w_o * fmaxf(a0, 0.0f);
        red[4*g+1] = h2w_o * fmaxf(a1, 0.0f);
        red[4*g+2] = h2w_o * fmaxf(a2, 0.0f);
        red[4*g+3] = h2w_o * fmaxf(a3, 0.0f);
      }
      #pragma unroll
      for (int c = 0; c < 8; c++) {
        float v = red[c];
        v += __shfl_down(v, 32);
        v += __shfl_down(v, 16);
        v += __shfl_down(v, 8);
        v += __shfl_down(v, 4);
        v += __shfl_down(v, 2);
        v += __shfl_down(v, 1);
        if (o == 0) out[(size_t)t * N + n0 + hn0 + c] = sigmoidf_(v + h2b_s);
      }
    }
    __syncthreads();
  }
}

extern "C" void kernel_launch(void* const* d_in, const int* in_sizes, int n_in,
                              void* d_out, int out_size, void* d_ws, size_t ws_size,
                              hipStream_t stream) {
  const float* Xs   = (const float*)d_in[0];
  const float* Xd   = (const float*)d_in[1];
  const int*   erow = (const int*)d_in[2];
  const int*   ecol = (const int*)d_in[3];
  const float* evl  = (const float*)d_in[4];
  const float* g1W  = (const float*)d_in[5];
  const float* g1b  = (const float*)d_in[6];
  const float* g2W  = (const float*)d_in[7];
  const float* g2b  = (const float*)d_in[8];
  const float* Wih  = (const float*)d_in[9];
  const float* Whh  = (const float*)d_in[10];
  const float* bih  = (const float*)d_in[11];
  const float* bhh  = (const float*)d_in[12];
  const float* h1W  = (const float*)d_in[13];
  const float* h1b  = (const float*)d_in[14];
  const float* h2W  = (const float*)d_in[15];
  const float* h2b  = (const float*)d_in[16];

  const int N = in_sizes[0] / 32;
  const int E = in_sizes[2];
  const int T = in_sizes[1] / (N * 8);

  float* out  = (float*)d_out;
  float* buf0 = (float*)d_ws;                 // N*32 floats
  float* buf1 = buf0 + (size_t)N * 32;        // N*32 floats

  const int linBlocks  = (N + 7) / 8;
  const int spmmBlocks = (int)(((long)E * 8 + 255) / 256);

  // GraphConv 1: Xw1 = Xs @ g1W^T + g1b  -> buf0
  lin32_kernel<false><<<linBlocks, 256, 0, stream>>>(Xs, g1W, g1b, buf0, N);
  // acc1 = A_hat @ Xw1 -> buf1
  hipMemsetAsync(buf1, 0, (size_t)N * 32 * sizeof(float), stream);
  spmm_kernel<<<spmmBlocks, 256, 0, stream>>>(erow, ecol, evl, buf0, buf1, E);
  // GraphConv 2: Xw2 = relu(acc1) @ g2W^T + g2b -> buf0
  lin32_kernel<true><<<linBlocks, 256, 0, stream>>>(buf1, g2W, g2b, buf0, N);
  // acc2 = A_hat @ Xw2 -> buf1   (relu applied inside GRU kernel)
  hipMemsetAsync(buf1, 0, (size_t)N * 32 * sizeof(float), stream);
  spmm_kernel<<<spmmBlocks, 256, 0, stream>>>(erow, ecol, evl, buf0, buf1, E);
  // fused GRU + head
  gru_head_kernel<<<N / NB, 256, 0, stream>>>(buf1, Xd, Wih, Whh, bih, bhh,
                                              h1W, h1b, h2W, h2b, out, N, T);
}

// Round 2
// 1217.236 us; speedup vs baseline: 4.8041x; 4.8041x over previous
//
#include <hip/hip_runtime.h>
#include <math.h>

typedef short bf16x8_t __attribute__((ext_vector_type(8)));
typedef float f32x4_t  __attribute__((ext_vector_type(4)));

__device__ __forceinline__ float sigmoidf_(float x) { return 1.0f / (1.0f + __expf(-x)); }
__device__ __forceinline__ float tanhf_(float x) {
  x = fminf(fmaxf(x, -10.0f), 10.0f);
  float e = __expf(2.0f * x);
  return (e - 1.0f) / (e + 1.0f);
}
__device__ __forceinline__ unsigned short f2bf(float f) {
  unsigned int u = __float_as_uint(f);
  unsigned int r = (u + 0x7fffu + ((u >> 16) & 1u)) >> 16;
  return (unsigned short)r;
}

// ---------- dense 32-in/32-out linear: out = [relu?](X) @ W^T + b ----------
template<bool RELU_IN>
__global__ __launch_bounds__(256) void lin32_kernel(
    const float* __restrict__ X, const float* __restrict__ W,
    const float* __restrict__ b, float* __restrict__ out, int N)
{
  __shared__ float sW[32][33];
  __shared__ float sb[32];
  __shared__ float sX[8][33];
  const int tid = threadIdx.x;
  for (int i = tid; i < 1024; i += 256) sW[i >> 5][i & 31] = W[i];
  if (tid < 32) sb[tid] = b[tid];
  const int n0 = blockIdx.x * 8;
  {
    float v = X[(size_t)n0 * 32 + tid];
    if (RELU_IN) v = fmaxf(v, 0.0f);
    sX[tid >> 5][tid & 31] = v;
  }
  __syncthreads();
  const int ln = tid >> 5, f = tid & 31;
  float acc = sb[f];
  #pragma unroll
  for (int j = 0; j < 32; j++) acc += sX[ln][j] * sW[f][j];
  out[(size_t)n0 * 32 + tid] = acc;
}

// ---------- fallback SpMM (atomics) ----------
__global__ __launch_bounds__(256) void spmm_kernel(
    const int* __restrict__ erow, const int* __restrict__ ecol,
    const float* __restrict__ eval, const float* __restrict__ X,
    float* __restrict__ out, int E)
{
  const long gid = (long)blockIdx.x * 256 + threadIdx.x;
  const int e = (int)(gid >> 3);
  const int q = (int)(gid & 7);
  if (e >= E) return;
  const int r = erow[e], c = ecol[e];
  const float v = eval[e];
  const float4 x = *(const float4*)(X + (size_t)c * 32 + q * 4);
  float* o = out + (size_t)r * 32 + q * 4;
  atomicAdd(o + 0, v * x.x);
  atomicAdd(o + 1, v * x.y);
  atomicAdd(o + 2, v * x.z);
  atomicAdd(o + 3, v * x.w);
}

// ---------- CSR build ----------
__global__ __launch_bounds__(256) void hist_k(const int* __restrict__ erow, int* cnt, int E) {
  int e = blockIdx.x * 256 + threadIdx.x;
  if (e < E) atomicAdd(&cnt[erow[e]], 1);
}

__global__ __launch_bounds__(256) void scan1_k(const int* __restrict__ cnt, int* startv, int* bsum, int N) {
  __shared__ int s[256];
  int t = threadIdx.x, i = blockIdx.x * 256 + t;
  int v = (i < N) ? cnt[i] : 0;
  s[t] = v; __syncthreads();
  for (int off = 1; off < 256; off <<= 1) {
    int u = (t >= off) ? s[t - off] : 0;
    __syncthreads(); s[t] += u; __syncthreads();
  }
  if (i < N) startv[i] = s[t] - v;
  if (t == 255) bsum[blockIdx.x] = s[255];
}

__global__ __launch_bounds__(512) void scan2_k(const int* __restrict__ bsum, int* bsumx, int nb) {
  __shared__ int s[512];
  int t = threadIdx.x;
  int v = (t < nb) ? bsum[t] : 0;
  s[t] = v; __syncthreads();
  for (int off = 1; off < 512; off <<= 1) {
    int u = (t >= off) ? s[t - off] : 0;
    __syncthreads(); s[t] += u; __syncthreads();
  }
  if (t < nb) bsumx[t] = s[t] - v;
}

__global__ __launch_bounds__(256) void scan3_k(int* startv, const int* __restrict__ bsumx, int* cursor, int N) {
  int i = blockIdx.x * 256 + threadIdx.x;
  if (i < N) {
    int v = startv[i] + bsumx[i >> 8];
    startv[i] = v;
    cursor[i] = v;
  }
}

__global__ __launch_bounds__(256) void scatter_k(
    const int* __restrict__ erow, const int* __restrict__ ecol,
    const float* __restrict__ evl, int* cursor, int2* __restrict__ pairs, int E)
{
  int e = blockIdx.x * 256 + threadIdx.x;
  if (e < E) {
    int r = erow[e];
    int p = atomicAdd(&cursor[r], 1);
    pairs[p] = make_int2(ecol[e], __float_as_int(evl[e]));
  }
}

// one wave per row, lanes 0-31 = features, two edges in flight per wave
__global__ __launch_bounds__(256) void spmm_csr_k(
    const int* __restrict__ startv, const int* __restrict__ cnt,
    const int2* __restrict__ pairs, const float* __restrict__ X,
    float* __restrict__ out, int N)
{
  int row = blockIdx.x * 4 + (threadIdx.x >> 6);
  if (row >= N) return;
  int lane = threadIdx.x & 63;
  int f = lane & 31, hh = lane >> 5;
  int base = startv[row], len = cnt[row];
  float acc = 0.0f;
  for (int i = hh; i < len; i += 2) {
    int2 p = pairs[base + i];
    acc += __int_as_float(p.y) * X[(size_t)p.x * 32 + f];
  }
  acc += __shfl_down(acc, 32);
  if (hh == 0) out[(size_t)row * 32 + f] = acc;
}

// ---------- fused MFMA GRU + head, 32 nodes / block ----------
#define NB 32

__global__ __launch_bounds__(256, 2) void gru_head_mfma(
    const float* __restrict__ acc2,   // (N,32) pre-relu graph output
    const float* __restrict__ xdyn,   // (T,N,8)
    const float* __restrict__ Wih,    // (192,40)
    const float* __restrict__ Whh,    // (192,64)
    const float* __restrict__ bih, const float* __restrict__ bhh,
    const float* __restrict__ h1W,    // (64,64)
    const float* __restrict__ h1b, const float* __restrict__ h2W,
    const float* __restrict__ h2b,
    float* __restrict__ out, int N, int T)
{
  __shared__ __align__(16) unsigned short z[32][104];  // Z matrix [n][k] bf16, k<96 used
  __shared__ float s_red[32][17];

  const int tid  = threadIdx.x;
  const int w    = tid >> 6;       // wave 0..3
  const int lane = tid & 63;
  const int ml   = lane & 15;      // A-row / B-col / D-col within tile
  const int q    = lane >> 4;      // quad
  const int n0   = blockIdx.x * NB;

  // ---- A fragments (weights), built once, live in registers ----
  // wave w owns m-tiles {w, w+4, w+8, w+12} => gate groups r/z/i_n/h_n for rows j in [16w,16w+16)
  bf16x8_t Am[4][3];
  #pragma unroll
  for (int g = 0; g < 4; g++) {
    #pragma unroll
    for (int s = 0; s < 3; s++) {
      union { bf16x8_t v; unsigned short u[8]; } tmp;
      #pragma unroll
      for (int jj = 0; jj < 8; jj++) {
        int k = s * 32 + q * 8 + jj;
        int j = 16 * w + ml;
        float val = 0.0f;
        if (g == 0)      val = (k < 64) ? Whh[j * 64 + k]          : (k < 72 ? Wih[j * 40 + 32 + (k - 64)] : 0.0f);
        else if (g == 1) val = (k < 64) ? Whh[(64 + j) * 64 + k]   : (k < 72 ? Wih[(64 + j) * 40 + 32 + (k - 64)] : 0.0f);
        else if (g == 2) val = (k >= 64 && k < 72) ? Wih[(128 + j) * 40 + 32 + (k - 64)] : 0.0f;
        else             val = (k < 64) ? Whh[(128 + j) * 64 + k]  : 0.0f;
        tmp.u[jj] = f2bf(val);
      }
      Am[g][s] = tmp.v;
    }
  }
  bf16x8_t Ag[3];   // static gi projection W_is rows (K=32)
  #pragma unroll
  for (int g = 0; g < 3; g++) {
    union { bf16x8_t v; unsigned short u[8]; } tmp;
    #pragma unroll
    for (int jj = 0; jj < 8; jj++)
      tmp.u[jj] = f2bf(Wih[(g * 64 + 16 * w + ml) * 40 + q * 8 + jj]);
    Ag[g] = tmp.v;
  }
  bf16x8_t Ah[2];   // head h1W (64x64), wave w owns o-rows [16w,16w+16)
  #pragma unroll
  for (int s = 0; s < 2; s++) {
    union { bf16x8_t v; unsigned short u[8]; } tmp;
    #pragma unroll
    for (int jj = 0; jj < 8; jj++)
      tmp.u[jj] = f2bf(h1W[(16 * w + ml) * 64 + s * 32 + q * 8 + jj]);
    Ah[s] = tmp.v;
  }

  // per-reg scalars (j = 16w + 4q + reg)
  float bias_r[4], bias_z[4], bias_in[4], bhh_n[4], h1b_r[4], h2w_r[4];
  #pragma unroll
  for (int reg = 0; reg < 4; reg++) {
    int j = 16 * w + 4 * q + reg;
    bias_r[reg]  = bih[j] + bhh[j];
    bias_z[reg]  = bih[64 + j] + bhh[64 + j];
    bias_in[reg] = bih[128 + j];
    bhh_n[reg]   = bhh[128 + j];
    h1b_r[reg]   = h1b[j];
    h2w_r[reg]   = h2W[j];
  }
  const float h2b0 = h2b[0];

  // ---- stage hg = relu(acc2) as bf16 into z rows k<32 ----
  {
    int nd = tid >> 3, f0 = (tid & 7) * 4;
    float4 v = *(const float4*)(acc2 + (size_t)(n0 + nd) * 32 + f0);
    unsigned long long pk =
        (unsigned long long)f2bf(fmaxf(v.x, 0.0f)) |
        ((unsigned long long)f2bf(fmaxf(v.y, 0.0f)) << 16) |
        ((unsigned long long)f2bf(fmaxf(v.z, 0.0f)) << 32) |
        ((unsigned long long)f2bf(fmaxf(v.w, 0.0f)) << 48);
    *(unsigned long long*)&z[nd][f0] = pk;
  }
  __syncthreads();

  // gis = W_is @ hg^T  (one K=32 step)
  f32x4_t gis[3][2];
  {
    bf16x8_t Bg[2];
    #pragma unroll
    for (int nt = 0; nt < 2; nt++)
      Bg[nt] = *(const bf16x8_t*)&z[nt * 16 + ml][q * 8];
    f32x4_t zero = {0.0f, 0.0f, 0.0f, 0.0f};
    #pragma unroll
    for (int g = 0; g < 3; g++)
      #pragma unroll
      for (int nt = 0; nt < 2; nt++)
        gis[g][nt] = __builtin_amdgcn_mfma_f32_16x16x32_bf16(Ag[g], Bg[nt], zero, 0, 0, 0);
  }
  __syncthreads();   // gis B-reads complete before zeroing

  // zero all of z (h0 = 0, pad rows = 0)
  for (int i = tid; i < 32 * 104 / 2; i += 256) ((unsigned int*)z)[i] = 0;
  #pragma unroll
  for (int nt = 0; nt < 2; nt++)
    #pragma unroll
    for (int reg = 0; reg < 4; reg++) {
      gis[0][nt][reg] += bias_r[reg];
      gis[1][nt][reg] += bias_z[reg];
      gis[2][nt][reg] += bias_in[reg];
    }
  __syncthreads();

  float hreg[2][4] = {{0, 0, 0, 0}, {0, 0, 0, 0}};   // h state in registers

  for (int t = 0; t < T; t++) {
    if (t) __syncthreads();   // B1: s_red reads + prior-step LDS reads done

    // stage xd(t) bf16 -> z rows [64,72)
    if (tid < 64) {
      float4 v = *(const float4*)(xdyn + ((size_t)t * N + n0) * 8 + tid * 4);
      int nd = tid >> 1, f0 = (tid & 1) * 4;
      unsigned long long pk =
          (unsigned long long)f2bf(v.x) |
          ((unsigned long long)f2bf(v.y) << 16) |
          ((unsigned long long)f2bf(v.z) << 32) |
          ((unsigned long long)f2bf(v.w) << 48);
      *(unsigned long long*)&z[nd][64 + f0] = pk;
    }
    __syncthreads();   // B2: xd visible (h_{t-1} already in place)

    // load all B fragments for main GEMM
    bf16x8_t Bf[2][3];
    #pragma unroll
    for (int nt = 0; nt < 2; nt++)
      #pragma unroll
      for (int s = 0; s < 3; s++)
        Bf[nt][s] = *(const bf16x8_t*)&z[nt * 16 + ml][s * 32 + q * 8];
    __syncthreads();   // B2b: all reads in-flight drained; safe to overwrite h rows

    // main GEMM: skip known-zero A fragments (g=2: only s=2; g=3: only s<2)
    f32x4_t acc[4][2];
    #pragma unroll
    for (int g = 0; g < 4; g++)
      #pragma unroll
      for (int nt = 0; nt < 2; nt++)
        acc[g][nt] = (f32x4_t){0.0f, 0.0f, 0.0f, 0.0f};
    #pragma unroll
    for (int nt = 0; nt < 2; nt++) {
      #pragma unroll
      for (int s = 0; s < 3; s++) {
        acc[0][nt] = __builtin_amdgcn_mfma_f32_16x16x32_bf16(Am[0][s], Bf[nt][s], acc[0][nt], 0, 0, 0);
        acc[1][nt] = __builtin_amdgcn_mfma_f32_16x16x32_bf16(Am[1][s], Bf[nt][s], acc[1][nt], 0, 0, 0);
      }
      acc[2][nt] = __builtin_amdgcn_mfma_f32_16x16x32_bf16(Am[2][2], Bf[nt][2], acc[2][nt], 0, 0, 0);
      acc[3][nt] = __builtin_amdgcn_mfma_f32_16x16x32_bf16(Am[3][0], Bf[nt][0], acc[3][nt], 0, 0, 0);
      acc[3][nt] = __builtin_amdgcn_mfma_f32_16x16x32_bf16(Am[3][1], Bf[nt][1], acc[3][nt], 0, 0, 0);
    }

    // epilogue: gate nonlinearities + state update, all in registers
    #pragma unroll
    for (int nt = 0; nt < 2; nt++) {
      unsigned short hb[4];
      #pragma unroll
      for (int reg = 0; reg < 4; reg++) {
        float r  = sigmoidf_(gis[0][nt][reg] + acc[0][nt][reg]);
        float zg = sigmoidf_(gis[1][nt][reg] + acc[1][nt][reg]);
        float hn = bhh_n[reg] + acc[3][nt][reg];
        float nn = tanhf_(gis[2][nt][reg] + acc[2][nt][reg] + r * hn);
        float h  = (1.0f - zg) * nn + zg * hreg[nt][reg];
        hreg[nt][reg] = h;
        hb[reg] = f2bf(h);
      }
      unsigned long long pk =
          (unsigned long long)hb[0] | ((unsigned long long)hb[1] << 16) |
          ((unsigned long long)hb[2] << 32) | ((unsigned long long)hb[3] << 48);
      *(unsigned long long*)&z[nt * 16 + ml][16 * w + 4 * q] = pk;
    }
    __syncthreads();   // B3: h_t visible

    // head GEMM: relu(h1W @ h + h1b) dot h2W
    bf16x8_t Hb[2][2];
    #pragma unroll
    for (int nt = 0; nt < 2; nt++)
      #pragma unroll
      for (int s = 0; s < 2; s++)
        Hb[nt][s] = *(const bf16x8_t*)&z[nt * 16 + ml][s * 32 + q * 8];
    #pragma unroll
    for (int nt = 0; nt < 2; nt++) {
      f32x4_t hacc = {0.0f, 0.0f, 0.0f, 0.0f};
      hacc = __builtin_amdgcn_mfma_f32_16x16x32_bf16(Ah[0], Hb[nt][0], hacc, 0, 0, 0);
      hacc = __builtin_amdgcn_mfma_f32_16x16x32_bf16(Ah[1], Hb[nt][1], hacc, 0, 0, 0);
      float p = 0.0f;
      #pragma unroll
      for (int reg = 0; reg < 4; reg++)
        p += h2w_r[reg] * fmaxf(hacc[reg] + h1b_r[reg], 0.0f);
      s_red[nt * 16 + ml][w * 4 + q] = p;
    }
    __syncthreads();   // B4: partials ready

    if (tid < 32) {
      float s = 0.0f;
      #pragma unroll
      for (int i = 0; i < 16; i++) s += s_red[tid][i];
      out[(size_t)t * N + n0 + tid] = sigmoidf_(s + h2b0);
    }
  }
}

extern "C" void kernel_launch(void* const* d_in, const int* in_sizes, int n_in,
                              void* d_out, int out_size, void* d_ws, size_t ws_size,
                              hipStream_t stream) {
  const float* Xs   = (const float*)d_in[0];
  const float* Xd   = (const float*)d_in[1];
  const int*   erow = (const int*)d_in[2];
  const int*   ecol = (const int*)d_in[3];
  const float* evl  = (const float*)d_in[4];
  const float* g1W  = (const float*)d_in[5];
  const float* g1b  = (const float*)d_in[6];
  const float* g2W  = (const float*)d_in[7];
  const float* g2b  = (const float*)d_in[8];
  const float* Wih  = (const float*)d_in[9];
  const float* Whh  = (const float*)d_in[10];
  const float* bih  = (const float*)d_in[11];
  const float* bhh  = (const float*)d_in[12];
  const float* h1W  = (const float*)d_in[13];
  const float* h1b  = (const float*)d_in[14];
  const float* h2W  = (const float*)d_in[15];
  const float* h2b  = (const float*)d_in[16];

  const int N = in_sizes[0] / 32;
  const int E = in_sizes[2];
  const int T = in_sizes[1] / (N * 8);

  float* out  = (float*)d_out;
  char*  base = (char*)d_ws;
  float* buf0 = (float*)base;                     // N*32
  float* buf1 = buf0 + (size_t)N * 32;            // N*32
  int*   cnt    = (int*)(buf1 + (size_t)N * 32);  // N
  int*   startv = cnt + N;                        // N
  int*   cursor = startv + N;                     // N
  int*   bsum   = cursor + N;                     // 512
  int*   bsumx  = bsum + 512;                     // 512
  int2*  pairs  = (int2*)(bsumx + 512);           // E

  const size_t needed = (size_t)((char*)(pairs + E) - base);
  const bool use_csr = (ws_size >= needed);

  const int linBlocks = (N + 7) / 8;
  const int eBlocks   = (E + 255) / 256;
  const int nb1       = (N + 255) / 256;

  // GraphConv 1 linear
  lin32_kernel<false><<<linBlocks, 256, 0, stream>>>(Xs, g1W, g1b, buf0, N);

  if (use_csr) {
    // build CSR once, reuse for both SpMM passes
    hipMemsetAsync(cnt, 0, (size_t)N * sizeof(int), stream);
    hist_k<<<eBlocks, 256, 0, stream>>>(erow, cnt, E);
    scan1_k<<<nb1, 256, 0, stream>>>(cnt, startv, bsum, N);
    scan2_k<<<1, 512, 0, stream>>>(bsum, bsumx, nb1);
    scan3_k<<<nb1, 256, 0, stream>>>(startv, bsumx, cursor, N);
    scatter_k<<<eBlocks, 256, 0, stream>>>(erow, ecol, evl, cursor, pairs, E);

    spmm_csr_k<<<(N + 3) / 4, 256, 0, stream>>>(startv, cnt, pairs, buf0, buf1, N);
    lin32_kernel<true><<<linBlocks, 256, 0, stream>>>(buf1, g2W, g2b, buf0, N);
    spmm_csr_k<<<(N + 3) / 4, 256, 0, stream>>>(startv, cnt, pairs, buf0, buf1, N);
  } else {
    const int spmmBlocks = (int)(((long)E * 8 + 255) / 256);
    hipMemsetAsync(buf1, 0, (size_t)N * 32 * sizeof(float), stream);
    spmm_kernel<<<spmmBlocks, 256, 0, stream>>>(erow, ecol, evl, buf0, buf1, E);
    lin32_kernel<true><<<linBlocks, 256, 0, stream>>>(buf1, g2W, g2b, buf0, N);
    hipMemsetAsync(buf1, 0, (size_t)N * 32 * sizeof(float), stream);
    spmm_kernel<<<spmmBlocks, 256, 0, stream>>>(erow, ecol, evl, buf0, buf1, E);
  }

  // fused MFMA GRU + head
  gru_head_mfma<<<N / NB, 256, 0, stream>>>(buf1, Xd, Wih, Whh, bih, bhh,
                                            h1W, h1b, h2W, h2b, out, N, T);
}

// Round 3
// 1087.168 us; speedup vs baseline: 5.3789x; 1.1196x over previous
//
#include <hip/hip_runtime.h>
#include <math.h>

typedef short bf16x8_t __attribute__((ext_vector_type(8)));
typedef float f32x4_t  __attribute__((ext_vector_type(4)));

__device__ __forceinline__ float sigmoidf_(float x) { return 1.0f / (1.0f + __expf(-x)); }
__device__ __forceinline__ float tanhf_(float x) {
  x = fminf(fmaxf(x, -10.0f), 10.0f);
  float e = __expf(2.0f * x);
  return (e - 1.0f) / (e + 1.0f);
}
__device__ __forceinline__ unsigned short f2bf(float f) {
  unsigned int u = __float_as_uint(f);
  unsigned int r = (u + 0x7fffu + ((u >> 16) & 1u)) >> 16;
  return (unsigned short)r;
}
__device__ __forceinline__ float bf2f(unsigned short u) {
  return __uint_as_float(((unsigned int)u) << 16);
}

// ---------- dense 32-in/32-out linear: out = [relu?](X) @ W^T + b ----------
template<bool RELU_IN, bool OUT_BF16>
__global__ __launch_bounds__(256) void lin32_kernel(
    const float* __restrict__ X, const float* __restrict__ W,
    const float* __restrict__ b, void* __restrict__ outp, int N)
{
  __shared__ float sW[32][33];
  __shared__ float sb[32];
  __shared__ float sX[8][33];
  const int tid = threadIdx.x;
  for (int i = tid; i < 1024; i += 256) sW[i >> 5][i & 31] = W[i];
  if (tid < 32) sb[tid] = b[tid];
  const int n0 = blockIdx.x * 8;
  {
    float v = X[(size_t)n0 * 32 + tid];
    if (RELU_IN) v = fmaxf(v, 0.0f);
    sX[tid >> 5][tid & 31] = v;
  }
  __syncthreads();
  const int ln = tid >> 5, f = tid & 31;
  float acc = sb[f];
  #pragma unroll
  for (int j = 0; j < 32; j++) acc += sX[ln][j] * sW[f][j];
  if (OUT_BF16) ((unsigned short*)outp)[(size_t)n0 * 32 + tid] = f2bf(acc);
  else          ((float*)outp)[(size_t)n0 * 32 + tid] = acc;
}

// ---------- fallback SpMM (atomics, fp32) ----------
__global__ __launch_bounds__(256) void spmm_kernel(
    const int* __restrict__ erow, const int* __restrict__ ecol,
    const float* __restrict__ eval, const float* __restrict__ X,
    float* __restrict__ out, int E)
{
  const long gid = (long)blockIdx.x * 256 + threadIdx.x;
  const int e = (int)(gid >> 3);
  const int q = (int)(gid & 7);
  if (e >= E) return;
  const int r = erow[e], c = ecol[e];
  const float v = eval[e];
  const float4 x = *(const float4*)(X + (size_t)c * 32 + q * 4);
  float* o = out + (size_t)r * 32 + q * 4;
  atomicAdd(o + 0, v * x.x);
  atomicAdd(o + 1, v * x.y);
  atomicAdd(o + 2, v * x.z);
  atomicAdd(o + 3, v * x.w);
}

// ---------- CSR build ----------
__global__ __launch_bounds__(256) void hist_k(const int* __restrict__ erow, int* cnt, int E) {
  int e = blockIdx.x * 256 + threadIdx.x;
  if (e < E) atomicAdd(&cnt[erow[e]], 1);
}

__global__ __launch_bounds__(256) void scan1_k(const int* __restrict__ cnt, int* startv, int* bsum, int N) {
  __shared__ int s[256];
  int t = threadIdx.x, i = blockIdx.x * 256 + t;
  int v = (i < N) ? cnt[i] : 0;
  s[t] = v; __syncthreads();
  for (int off = 1; off < 256; off <<= 1) {
    int u = (t >= off) ? s[t - off] : 0;
    __syncthreads(); s[t] += u; __syncthreads();
  }
  if (i < N) startv[i] = s[t] - v;
  if (t == 255) bsum[blockIdx.x] = s[255];
}

__global__ __launch_bounds__(512) void scan2_k(const int* __restrict__ bsum, int* bsumx, int nb) {
  __shared__ int s[512];
  int t = threadIdx.x;
  int v = (t < nb) ? bsum[t] : 0;
  s[t] = v; __syncthreads();
  for (int off = 1; off < 512; off <<= 1) {
    int u = (t >= off) ? s[t - off] : 0;
    __syncthreads(); s[t] += u; __syncthreads();
  }
  if (t < nb) bsumx[t] = s[t] - v;
}

__global__ __launch_bounds__(256) void scan3_k(int* startv, const int* __restrict__ bsumx, int* cursor, int N) {
  int i = blockIdx.x * 256 + threadIdx.x;
  if (i < N) {
    int v = startv[i] + bsumx[i >> 8];
    startv[i] = v;
    cursor[i] = v;
  }
}

__global__ __launch_bounds__(256) void scatter_k(
    const int* __restrict__ erow, const int* __restrict__ ecol,
    const float* __restrict__ evl, int* cursor, int2* __restrict__ pairs, int E)
{
  int e = blockIdx.x * 256 + threadIdx.x;
  if (e < E) {
    int r = erow[e];
    int p = atomicAdd(&cursor[r], 1);
    pairs[p] = make_int2(ecol[e], __float_as_int(evl[e]));
  }
}

// one wave per row; lanes 0-31 = features; 2 edges/iter, unrolled x4 (8 in flight)
__global__ __launch_bounds__(256) void spmm_csr_bf16_k(
    const int* __restrict__ startv, const int* __restrict__ cnt,
    const int2* __restrict__ pairs, const unsigned short* __restrict__ X,
    float* __restrict__ out, int N)
{
  int row = blockIdx.x * 4 + (threadIdx.x >> 6);
  if (row >= N) return;
  int lane = threadIdx.x & 63;
  int f = lane & 31, hh = lane >> 5;
  int base = startv[row] + hh;
  int len = cnt[row];
  float acc = 0.0f;
  int i = hh;
  for (; i + 6 < len; i += 8) {
    int2 p0 = pairs[base + 0];
    int2 p1 = pairs[base + 2];
    int2 p2 = pairs[base + 4];
    int2 p3 = pairs[base + 6];
    float x0 = bf2f(X[(size_t)p0.x * 32 + f]);
    float x1 = bf2f(X[(size_t)p1.x * 32 + f]);
    float x2 = bf2f(X[(size_t)p2.x * 32 + f]);
    float x3 = bf2f(X[(size_t)p3.x * 32 + f]);
    acc = fmaf(__int_as_float(p0.y), x0, acc);
    acc = fmaf(__int_as_float(p1.y), x1, acc);
    acc = fmaf(__int_as_float(p2.y), x2, acc);
    acc = fmaf(__int_as_float(p3.y), x3, acc);
    base += 8;
  }
  for (; i < len; i += 2) {
    int2 p = pairs[base];
    acc = fmaf(__int_as_float(p.y), bf2f(X[(size_t)p.x * 32 + f]), acc);
    base += 2;
  }
  acc += __shfl_down(acc, 32);
  if (hh == 0) out[(size_t)row * 32 + f] = acc;
}

// ---------- fused MFMA GRU + head, 32 nodes / block, double-buffered Z ----------
#define NB 32

__global__ __launch_bounds__(256, 4) void gru_head_mfma(
    const float* __restrict__ acc2,   // (N,32) pre-relu graph output
    const float* __restrict__ xdyn,   // (T,N,8)
    const float* __restrict__ Wih,    // (192,40)
    const float* __restrict__ Whh,    // (192,64)
    const float* __restrict__ bih, const float* __restrict__ bhh,
    const float* __restrict__ h1W,    // (64,64)
    const float* __restrict__ h1b, const float* __restrict__ h2W,
    const float* __restrict__ h2b,
    float* __restrict__ out, int N, int T)
{
  __shared__ __align__(16) unsigned short z[2][NB][104];  // [buf][n][k] bf16, k<96 used
  __shared__ float s_red[NB][5];

  const int tid  = threadIdx.x;
  const int w    = tid >> 6;       // wave 0..3
  const int lane = tid & 63;
  const int ml   = lane & 15;      // A-row / B-col within tile
  const int q    = lane >> 4;      // quad
  const int n0   = blockIdx.x * NB;

  // ---- A fragments (weights), built once; only the 9 nonzero ones ----
  // wave w covers gate rows j in [16w,16w+16); A-row m=ml, k=32s+8q+jj
  bf16x8_t A_r[3], A_z[3], A_in, A_hn[2];
  {
    const int j = 16 * w + ml;
    #pragma unroll
    for (int s = 0; s < 3; s++) {
      union { bf16x8_t v; unsigned short u[8]; } tr, tz;
      #pragma unroll
      for (int jj = 0; jj < 8; jj++) {
        int k = s * 32 + q * 8 + jj;
        float vr = (k < 64) ? Whh[j * 64 + k]        : (k < 72 ? Wih[j * 40 + 32 + (k - 64)] : 0.0f);
        float vz = (k < 64) ? Whh[(64 + j) * 64 + k] : (k < 72 ? Wih[(64 + j) * 40 + 32 + (k - 64)] : 0.0f);
        tr.u[jj] = f2bf(vr);
        tz.u[jj] = f2bf(vz);
      }
      A_r[s] = tr.v; A_z[s] = tz.v;
    }
    union { bf16x8_t v; unsigned short u[8]; } ti;
    #pragma unroll
    for (int jj = 0; jj < 8; jj++) {
      int kk = q * 8 + jj;  // k-64 within s=2 slab
      ti.u[jj] = f2bf((kk < 8) ? Wih[(128 + j) * 40 + 32 + kk] : 0.0f);
    }
    A_in = ti.v;
    #pragma unroll
    for (int s = 0; s < 2; s++) {
      union { bf16x8_t v; unsigned short u[8]; } th;
      #pragma unroll
      for (int jj = 0; jj < 8; jj++)
        th.u[jj] = f2bf(Whh[(128 + j) * 64 + s * 32 + q * 8 + jj]);
      A_hn[s] = th.v;
    }
  }
  bf16x8_t Ah[2];   // head h1W (64x64)
  #pragma unroll
  for (int s = 0; s < 2; s++) {
    union { bf16x8_t v; unsigned short u[8]; } tmp;
    #pragma unroll
    for (int jj = 0; jj < 8; jj++)
      tmp.u[jj] = f2bf(h1W[(16 * w + ml) * 64 + s * 32 + q * 8 + jj]);
    Ah[s] = tmp.v;
  }

  // per-reg persistent scalars (j = 16w + 4q + reg)
  float bhh_n[4], h1b_r[4], h2w_r[4];
  #pragma unroll
  for (int reg = 0; reg < 4; reg++) {
    int j = 16 * w + 4 * q + reg;
    bhh_n[reg] = bhh[128 + j];
    h1b_r[reg] = h1b[j];
    h2w_r[reg] = h2W[j];
  }
  const float h2b0 = h2b[0];

  // ---- stage hg = relu(acc2) bf16 into z[0] cols 0..32 ----
  {
    int nd = tid >> 3, f0 = (tid & 7) * 4;
    float4 v = *(const float4*)(acc2 + (size_t)(n0 + nd) * 32 + f0);
    unsigned long long pk =
        (unsigned long long)f2bf(fmaxf(v.x, 0.0f)) |
        ((unsigned long long)f2bf(fmaxf(v.y, 0.0f)) << 16) |
        ((unsigned long long)f2bf(fmaxf(v.z, 0.0f)) << 32) |
        ((unsigned long long)f2bf(fmaxf(v.w, 0.0f)) << 48);
    *(unsigned long long*)&z[0][nd][f0] = pk;
  }
  __syncthreads();

  // gis = W_is @ hg^T (K=32), biases folded in
  f32x4_t gis[3][2];
  {
    bf16x8_t Ag[3];
    #pragma unroll
    for (int g = 0; g < 3; g++) {
      union { bf16x8_t v; unsigned short u[8]; } tmp;
      #pragma unroll
      for (int jj = 0; jj < 8; jj++)
        tmp.u[jj] = f2bf(Wih[(g * 64 + 16 * w + ml) * 40 + q * 8 + jj]);
      Ag[g] = tmp.v;
    }
    bf16x8_t Bg[2];
    #pragma unroll
    for (int nt = 0; nt < 2; nt++)
      Bg[nt] = *(const bf16x8_t*)&z[0][nt * 16 + ml][q * 8];
    f32x4_t zero = {0.0f, 0.0f, 0.0f, 0.0f};
    #pragma unroll
    for (int g = 0; g < 3; g++)
      #pragma unroll
      for (int nt = 0; nt < 2; nt++)
        gis[g][nt] = __builtin_amdgcn_mfma_f32_16x16x32_bf16(Ag[g], Bg[nt], zero, 0, 0, 0);
  }
  __syncthreads();   // gis B-reads complete before zeroing

  for (int i = tid; i < 2 * NB * 104 / 2; i += 256) ((unsigned int*)z)[i] = 0;
  #pragma unroll
  for (int reg = 0; reg < 4; reg++) {
    int j = 16 * w + 4 * q + reg;
    float br = bih[j] + bhh[j];
    float bz = bih[64 + j] + bhh[64 + j];
    float bn = bih[128 + j];
    #pragma unroll
    for (int nt = 0; nt < 2; nt++) {
      gis[0][nt][reg] += br;
      gis[1][nt][reg] += bz;
      gis[2][nt][reg] += bn;
    }
  }
  __syncthreads();

  float hreg[2][4] = {{0, 0, 0, 0}, {0, 0, 0, 0}};

  // prefetch xd(0)
  float4 xv = make_float4(0.f, 0.f, 0.f, 0.f);
  if (tid < 64) xv = *(const float4*)(xdyn + (size_t)n0 * 8 + tid * 4);

  for (int t = 0; t < T; t++) {
    const int b = t & 1;
    // stage xd(t) into z[b] cols 64..72; prefetch xd(t+1)
    if (tid < 64) {
      unsigned long long pk =
          (unsigned long long)f2bf(xv.x) |
          ((unsigned long long)f2bf(xv.y) << 16) |
          ((unsigned long long)f2bf(xv.z) << 32) |
          ((unsigned long long)f2bf(xv.w) << 48);
      *(unsigned long long*)&z[b][tid >> 1][64 + (tid & 1) * 4] = pk;
      if (t + 1 < T)
        xv = *(const float4*)(xdyn + ((size_t)(t + 1) * N + n0) * 8 + tid * 4);
    }
    __syncthreads();   // S1: xd(t) visible; s_red(t-1) stable

    if (t && tid < 32) {
      float s = s_red[tid][0] + s_red[tid][1] + s_red[tid][2] + s_red[tid][3];
      out[(size_t)(t - 1) * N + n0 + tid] = sigmoidf_(s + h2b0);
    }

    // main GEMM + epilogue, per 16-node tile; h_t written to the OTHER buffer
    #pragma unroll
    for (int nt = 0; nt < 2; nt++) {
      bf16x8_t B0 = *(const bf16x8_t*)&z[b][nt * 16 + ml][q * 8];
      bf16x8_t B1 = *(const bf16x8_t*)&z[b][nt * 16 + ml][32 + q * 8];
      bf16x8_t B2 = *(const bf16x8_t*)&z[b][nt * 16 + ml][64 + q * 8];
      f32x4_t ar = {0.f, 0.f, 0.f, 0.f}, az = ar, ain = ar, ahn = ar;
      ar  = __builtin_amdgcn_mfma_f32_16x16x32_bf16(A_r[0], B0, ar, 0, 0, 0);
      az  = __builtin_amdgcn_mfma_f32_16x16x32_bf16(A_z[0], B0, az, 0, 0, 0);
      ahn = __builtin_amdgcn_mfma_f32_16x16x32_bf16(A_hn[0], B0, ahn, 0, 0, 0);
      ar  = __builtin_amdgcn_mfma_f32_16x16x32_bf16(A_r[1], B1, ar, 0, 0, 0);
      az  = __builtin_amdgcn_mfma_f32_16x16x32_bf16(A_z[1], B1, az, 0, 0, 0);
      ahn = __builtin_amdgcn_mfma_f32_16x16x32_bf16(A_hn[1], B1, ahn, 0, 0, 0);
      ar  = __builtin_amdgcn_mfma_f32_16x16x32_bf16(A_r[2], B2, ar, 0, 0, 0);
      az  = __builtin_amdgcn_mfma_f32_16x16x32_bf16(A_z[2], B2, az, 0, 0, 0);
      ain = __builtin_amdgcn_mfma_f32_16x16x32_bf16(A_in,  B2, ain, 0, 0, 0);

      unsigned short hb[4];
      #pragma unroll
      for (int reg = 0; reg < 4; reg++) {
        float r  = sigmoidf_(gis[0][nt][reg] + ar[reg]);
        float zg = sigmoidf_(gis[1][nt][reg] + az[reg]);
        float hn = bhh_n[reg] + ahn[reg];
        float nn = tanhf_(gis[2][nt][reg] + ain[reg] + r * hn);
        float h  = (1.0f - zg) * nn + zg * hreg[nt][reg];
        hreg[nt][reg] = h;
        hb[reg] = f2bf(h);
      }
      unsigned long long pk =
          (unsigned long long)hb[0] | ((unsigned long long)hb[1] << 16) |
          ((unsigned long long)hb[2] << 32) | ((unsigned long long)hb[3] << 48);
      *(unsigned long long*)&z[1 - b][nt * 16 + ml][16 * w + 4 * q] = pk;
    }
    __syncthreads();   // S2: h_t visible in z[1-b]

    // head: relu(h1W @ h_t + h1b) . h2W  -> per-wave partials via shfl
    #pragma unroll
    for (int nt = 0; nt < 2; nt++) {
      bf16x8_t H0 = *(const bf16x8_t*)&z[1 - b][nt * 16 + ml][q * 8];
      bf16x8_t H1 = *(const bf16x8_t*)&z[1 - b][nt * 16 + ml][32 + q * 8];
      f32x4_t ha = {0.f, 0.f, 0.f, 0.f};
      ha = __builtin_amdgcn_mfma_f32_16x16x32_bf16(Ah[0], H0, ha, 0, 0, 0);
      ha = __builtin_amdgcn_mfma_f32_16x16x32_bf16(Ah[1], H1, ha, 0, 0, 0);
      float p = 0.0f;
      #pragma unroll
      for (int reg = 0; reg < 4; reg++)
        p += h2w_r[reg] * fmaxf(ha[reg] + h1b_r[reg], 0.0f);
      p += __shfl_xor(p, 16, 64);
      p += __shfl_xor(p, 32, 64);
      if (q == 0) s_red[nt * 16 + ml][w] = p;
    }
    // no barrier: next S1 publishes s_red for the t+1 reduce
  }

  __syncthreads();
  if (tid < 32) {
    float s = s_red[tid][0] + s_red[tid][1] + s_red[tid][2] + s_red[tid][3];
    out[(size_t)(T - 1) * N + n0 + tid] = sigmoidf_(s + h2b0);
  }
}

extern "C" void kernel_launch(void* const* d_in, const int* in_sizes, int n_in,
                              void* d_out, int out_size, void* d_ws, size_t ws_size,
                              hipStream_t stream) {
  const float* Xs   = (const float*)d_in[0];
  const float* Xd   = (const float*)d_in[1];
  const int*   erow = (const int*)d_in[2];
  const int*   ecol = (const int*)d_in[3];
  const float* evl  = (const float*)d_in[4];
  const float* g1W  = (const float*)d_in[5];
  const float* g1b  = (const float*)d_in[6];
  const float* g2W  = (const float*)d_in[7];
  const float* g2b  = (const float*)d_in[8];
  const float* Wih  = (const float*)d_in[9];
  const float* Whh  = (const float*)d_in[10];
  const float* bih  = (const float*)d_in[11];
  const float* bhh  = (const float*)d_in[12];
  const float* h1W  = (const float*)d_in[13];
  const float* h1b  = (const float*)d_in[14];
  const float* h2W  = (const float*)d_in[15];
  const float* h2b  = (const float*)d_in[16];

  const int N = in_sizes[0] / 32;
  const int E = in_sizes[2];
  const int T = in_sizes[1] / (N * 8);

  float* out  = (float*)d_out;
  char*  base = (char*)d_ws;
  float* buf0 = (float*)base;                     // N*32 f32 (also aliased as bf16)
  float* buf1 = buf0 + (size_t)N * 32;            // N*32 f32
  int*   cnt    = (int*)(buf1 + (size_t)N * 32);  // N
  int*   startv = cnt + N;                        // N
  int*   cursor = startv + N;                     // N
  int*   bsum   = cursor + N;                     // 512
  int*   bsumx  = bsum + 512;                     // 512
  int2*  pairs  = (int2*)(bsumx + 512);           // E
  unsigned short* buf0h = (unsigned short*)buf0;  // bf16 view of buf0

  const size_t needed = (size_t)((char*)(pairs + E) - base);
  const bool use_csr = (ws_size >= needed);

  const int linBlocks = (N + 7) / 8;
  const int eBlocks   = (E + 255) / 256;
  const int nb1       = (N + 255) / 256;

  if (use_csr) {
    // GraphConv 1 linear -> bf16
    lin32_kernel<false, true><<<linBlocks, 256, 0, stream>>>(Xs, g1W, g1b, buf0h, N);

    // build CSR once
    hipMemsetAsync(cnt, 0, (size_t)N * sizeof(int), stream);
    hist_k<<<eBlocks, 256, 0, stream>>>(erow, cnt, E);
    scan1_k<<<nb1, 256, 0, stream>>>(cnt, startv, bsum, N);
    scan2_k<<<1, 512, 0, stream>>>(bsum, bsumx, nb1);
    scan3_k<<<nb1, 256, 0, stream>>>(startv, bsumx, cursor, N);
    scatter_k<<<eBlocks, 256, 0, stream>>>(erow, ecol, evl, cursor, pairs, E);

    spmm_csr_bf16_k<<<(N + 3) / 4, 256, 0, stream>>>(startv, cnt, pairs, buf0h, buf1, N);
    lin32_kernel<true, true><<<linBlocks, 256, 0, stream>>>(buf1, g2W, g2b, buf0h, N);
    spmm_csr_bf16_k<<<(N + 3) / 4, 256, 0, stream>>>(startv, cnt, pairs, buf0h, buf1, N);
  } else {
    lin32_kernel<false, false><<<linBlocks, 256, 0, stream>>>(Xs, g1W, g1b, buf0, N);
    const int spmmBlocks = (int)(((long)E * 8 + 255) / 256);
    hipMemsetAsync(buf1, 0, (size_t)N * 32 * sizeof(float), stream);
    spmm_kernel<<<spmmBlocks, 256, 0, stream>>>(erow, ecol, evl, buf0, buf1, E);
    lin32_kernel<true, false><<<linBlocks, 256, 0, stream>>>(buf1, g2W, g2b, buf0, N);
    hipMemsetAsync(buf1, 0, (size_t)N * 32 * sizeof(float), stream);
    spmm_kernel<<<spmmBlocks, 256, 0, stream>>>(erow, ecol, evl, buf0, buf1, E);
  }

  // fused MFMA GRU + head
  gru_head_mfma<<<N / NB, 256, 0, stream>>>(buf1, Xd, Wih, Whh, bih, bhh,
                                            h1W, h1b, h2W, h2b, out, N, T);
}

// Round 4
// 931.242 us; speedup vs baseline: 6.2795x; 1.1674x over previous
//
#include <hip/hip_runtime.h>
#include <math.h>

typedef short bf16x8_t __attribute__((ext_vector_type(8)));
typedef float f32x4_t  __attribute__((ext_vector_type(4)));

__device__ __forceinline__ float fast_rcp(float x) { return __builtin_amdgcn_rcpf(x); }
__device__ __forceinline__ float sigmoidf_(float x) {
  return fast_rcp(1.0f + __expf(-x));
}
__device__ __forceinline__ float tanhf_(float x) {
  // tanh(x) = 1 - 2/(e^{2x}+1); inf-safe without clamps (exp->inf => rcp->0 => 1)
  return fmaf(-2.0f, fast_rcp(__expf(2.0f * x) + 1.0f), 1.0f);
}
__device__ __forceinline__ unsigned short f2bf(float f) {
  unsigned int u = __float_as_uint(f);
  unsigned int r = (u + 0x7fffu + ((u >> 16) & 1u)) >> 16;
  return (unsigned short)r;
}
__device__ __forceinline__ float bf2f(unsigned short u) {
  return __uint_as_float(((unsigned int)u) << 16);
}

// ---------- dense 32-in/32-out linear: out = [relu?](X) @ W^T + b ----------
template<bool RELU_IN, bool OUT_BF16>
__global__ __launch_bounds__(256) void lin32_kernel(
    const float* __restrict__ X, const float* __restrict__ W,
    const float* __restrict__ b, void* __restrict__ outp, int N)
{
  __shared__ float sW[32][33];
  __shared__ float sb[32];
  __shared__ float sX[8][33];
  const int tid = threadIdx.x;
  for (int i = tid; i < 1024; i += 256) sW[i >> 5][i & 31] = W[i];
  if (tid < 32) sb[tid] = b[tid];
  const int n0 = blockIdx.x * 8;
  {
    float v = X[(size_t)n0 * 32 + tid];
    if (RELU_IN) v = fmaxf(v, 0.0f);
    sX[tid >> 5][tid & 31] = v;
  }
  __syncthreads();
  const int ln = tid >> 5, f = tid & 31;
  float acc = sb[f];
  #pragma unroll
  for (int j = 0; j < 32; j++) acc += sX[ln][j] * sW[f][j];
  if (OUT_BF16) ((unsigned short*)outp)[(size_t)n0 * 32 + tid] = f2bf(acc);
  else          ((float*)outp)[(size_t)n0 * 32 + tid] = acc;
}

// ---------- fallback SpMM (atomics, fp32) ----------
__global__ __launch_bounds__(256) void spmm_kernel(
    const int* __restrict__ erow, const int* __restrict__ ecol,
    const float* __restrict__ eval, const float* __restrict__ X,
    float* __restrict__ out, int E)
{
  const long gid = (long)blockIdx.x * 256 + threadIdx.x;
  const int e = (int)(gid >> 3);
  const int q = (int)(gid & 7);
  if (e >= E) return;
  const int r = erow[e], c = ecol[e];
  const float v = eval[e];
  const float4 x = *(const float4*)(X + (size_t)c * 32 + q * 4);
  float* o = out + (size_t)r * 32 + q * 4;
  atomicAdd(o + 0, v * x.x);
  atomicAdd(o + 1, v * x.y);
  atomicAdd(o + 2, v * x.z);
  atomicAdd(o + 3, v * x.w);
}

// ---------- CSR build ----------
__global__ __launch_bounds__(256) void hist_k(const int* __restrict__ erow, int* cnt, int E) {
  int e = blockIdx.x * 256 + threadIdx.x;
  if (e < E) atomicAdd(&cnt[erow[e]], 1);
}

__global__ __launch_bounds__(256) void scan1_k(const int* __restrict__ cnt, int* startv, int* bsum, int N) {
  __shared__ int s[256];
  int t = threadIdx.x, i = blockIdx.x * 256 + t;
  int v = (i < N) ? cnt[i] : 0;
  s[t] = v; __syncthreads();
  for (int off = 1; off < 256; off <<= 1) {
    int u = (t >= off) ? s[t - off] : 0;
    __syncthreads(); s[t] += u; __syncthreads();
  }
  if (i < N) startv[i] = s[t] - v;
  if (t == 255) bsum[blockIdx.x] = s[255];
}

__global__ __launch_bounds__(512) void scan2_k(const int* __restrict__ bsum, int* bsumx, int nb) {
  __shared__ int s[512];
  int t = threadIdx.x;
  int v = (t < nb) ? bsum[t] : 0;
  s[t] = v; __syncthreads();
  for (int off = 1; off < 512; off <<= 1) {
    int u = (t >= off) ? s[t - off] : 0;
    __syncthreads(); s[t] += u; __syncthreads();
  }
  if (t < nb) bsumx[t] = s[t] - v;
}

__global__ __launch_bounds__(256) void scan3_k(int* startv, const int* __restrict__ bsumx, int* cursor, int N) {
  int i = blockIdx.x * 256 + threadIdx.x;
  if (i < N) {
    int v = startv[i] + bsumx[i >> 8];
    startv[i] = v;
    cursor[i] = v;
  }
}

__global__ __launch_bounds__(256) void scatter_k(
    const int* __restrict__ erow, const int* __restrict__ ecol,
    const float* __restrict__ evl, int* cursor, int2* __restrict__ pairs, int E)
{
  int e = blockIdx.x * 256 + threadIdx.x;
  if (e < E) {
    int r = erow[e];
    int p = atomicAdd(&cursor[r], 1);
    pairs[p] = make_int2(ecol[e], __float_as_int(evl[e]));
  }
}

// one wave per row; lanes 0-31 = features; 2 edges/iter, unrolled x4 (8 in flight)
__global__ __launch_bounds__(256) void spmm_csr_bf16_k(
    const int* __restrict__ startv, const int* __restrict__ cnt,
    const int2* __restrict__ pairs, const unsigned short* __restrict__ X,
    float* __restrict__ out, int N)
{
  int row = blockIdx.x * 4 + (threadIdx.x >> 6);
  if (row >= N) return;
  int lane = threadIdx.x & 63;
  int f = lane & 31, hh = lane >> 5;
  int base = startv[row] + hh;
  int len = cnt[row];
  float acc = 0.0f;
  int i = hh;
  for (; i + 6 < len; i += 8) {
    int2 p0 = pairs[base + 0];
    int2 p1 = pairs[base + 2];
    int2 p2 = pairs[base + 4];
    int2 p3 = pairs[base + 6];
    float x0 = bf2f(X[(size_t)p0.x * 32 + f]);
    float x1 = bf2f(X[(size_t)p1.x * 32 + f]);
    float x2 = bf2f(X[(size_t)p2.x * 32 + f]);
    float x3 = bf2f(X[(size_t)p3.x * 32 + f]);
    acc = fmaf(__int_as_float(p0.y), x0, acc);
    acc = fmaf(__int_as_float(p1.y), x1, acc);
    acc = fmaf(__int_as_float(p2.y), x2, acc);
    acc = fmaf(__int_as_float(p3.y), x3, acc);
    base += 8;
  }
  for (; i < len; i += 2) {
    int2 p = pairs[base];
    acc = fmaf(__int_as_float(p.y), bf2f(X[(size_t)p.x * 32 + f]), acc);
    base += 2;
  }
  acc += __shfl_down(acc, 32);
  if (hh == 0) out[(size_t)row * 32 + f] = acc;
}

// ---------- fused MFMA GRU + head, 32 nodes / block ----------
// ONE barrier per time step: head(t-1) reuses the main GEMM's B0/B1 fragments
// (h_{t-1} rows), epilogue writes h_t to the other Z buffer, s_red double-buffered.
#define NB 32

__global__ __launch_bounds__(256, 2) void gru_head_mfma(
    const float* __restrict__ acc2,   // (N,32) pre-relu graph output
    const float* __restrict__ xdyn,   // (T,N,8)
    const float* __restrict__ Wih,    // (192,40)
    const float* __restrict__ Whh,    // (192,64)
    const float* __restrict__ bih, const float* __restrict__ bhh,
    const float* __restrict__ h1W,    // (64,64)
    const float* __restrict__ h1b, const float* __restrict__ h2W,
    const float* __restrict__ h2b,
    float* __restrict__ out, int N, int T)
{
  __shared__ __align__(16) unsigned short z[2][NB][104];  // [buf][n][k] bf16
  __shared__ float s_red[2][NB][5];                       // double-buffered head partials

  const int tid  = threadIdx.x;
  const int w    = tid >> 6;       // wave 0..3
  const int lane = tid & 63;
  const int ml   = lane & 15;      // A-row / B-col within tile
  const int q    = lane >> 4;      // quad
  const int n0   = blockIdx.x * NB;

  // ---- A fragments (weights), built once; only the 9 nonzero ones ----
  bf16x8_t A_r[3], A_z[3], A_in, A_hn[2];
  {
    const int j = 16 * w + ml;
    #pragma unroll
    for (int s = 0; s < 3; s++) {
      union { bf16x8_t v; unsigned short u[8]; } tr, tz;
      #pragma unroll
      for (int jj = 0; jj < 8; jj++) {
        int k = s * 32 + q * 8 + jj;
        float vr = (k < 64) ? Whh[j * 64 + k]        : (k < 72 ? Wih[j * 40 + 32 + (k - 64)] : 0.0f);
        float vz = (k < 64) ? Whh[(64 + j) * 64 + k] : (k < 72 ? Wih[(64 + j) * 40 + 32 + (k - 64)] : 0.0f);
        tr.u[jj] = f2bf(vr);
        tz.u[jj] = f2bf(vz);
      }
      A_r[s] = tr.v; A_z[s] = tz.v;
    }
    union { bf16x8_t v; unsigned short u[8]; } ti;
    #pragma unroll
    for (int jj = 0; jj < 8; jj++) {
      int kk = q * 8 + jj;
      ti.u[jj] = f2bf((kk < 8) ? Wih[(128 + j) * 40 + 32 + kk] : 0.0f);
    }
    A_in = ti.v;
    #pragma unroll
    for (int s = 0; s < 2; s++) {
      union { bf16x8_t v; unsigned short u[8]; } th;
      #pragma unroll
      for (int jj = 0; jj < 8; jj++)
        th.u[jj] = f2bf(Whh[(128 + j) * 64 + s * 32 + q * 8 + jj]);
      A_hn[s] = th.v;
    }
  }
  bf16x8_t Ah[2];   // head h1W (64x64), wave w owns o-rows [16w,16w+16)
  #pragma unroll
  for (int s = 0; s < 2; s++) {
    union { bf16x8_t v; unsigned short u[8]; } tmp;
    #pragma unroll
    for (int jj = 0; jj < 8; jj++)
      tmp.u[jj] = f2bf(h1W[(16 * w + ml) * 64 + s * 32 + q * 8 + jj]);
    Ah[s] = tmp.v;
  }

  // per-reg persistent scalars (j = 16w + 4q + reg)
  float bhh_n[4], h1b_r[4], h2w_r[4];
  #pragma unroll
  for (int reg = 0; reg < 4; reg++) {
    int j = 16 * w + 4 * q + reg;
    bhh_n[reg] = bhh[128 + j];
    h1b_r[reg] = h1b[j];
    h2w_r[reg] = h2W[j];
  }
  const float h2b0 = h2b[0];

  // ---- stage hg = relu(acc2) bf16 into z[0] cols 0..32 ----
  {
    int nd = tid >> 3, f0 = (tid & 7) * 4;
    float4 v = *(const float4*)(acc2 + (size_t)(n0 + nd) * 32 + f0);
    unsigned long long pk =
        (unsigned long long)f2bf(fmaxf(v.x, 0.0f)) |
        ((unsigned long long)f2bf(fmaxf(v.y, 0.0f)) << 16) |
        ((unsigned long long)f2bf(fmaxf(v.z, 0.0f)) << 32) |
        ((unsigned long long)f2bf(fmaxf(v.w, 0.0f)) << 48);
    *(unsigned long long*)&z[0][nd][f0] = pk;
  }
  __syncthreads();

  // gis = W_is @ hg^T (K=32), biases folded in
  f32x4_t gis[3][2];
  {
    bf16x8_t Ag[3];
    #pragma unroll
    for (int g = 0; g < 3; g++) {
      union { bf16x8_t v; unsigned short u[8]; } tmp;
      #pragma unroll
      for (int jj = 0; jj < 8; jj++)
        tmp.u[jj] = f2bf(Wih[(g * 64 + 16 * w + ml) * 40 + q * 8 + jj]);
      Ag[g] = tmp.v;
    }
    bf16x8_t Bg[2];
    #pragma unroll
    for (int nt = 0; nt < 2; nt++)
      Bg[nt] = *(const bf16x8_t*)&z[0][nt * 16 + ml][q * 8];
    f32x4_t zero = {0.0f, 0.0f, 0.0f, 0.0f};
    #pragma unroll
    for (int g = 0; g < 3; g++)
      #pragma unroll
      for (int nt = 0; nt < 2; nt++)
        gis[g][nt] = __builtin_amdgcn_mfma_f32_16x16x32_bf16(Ag[g], Bg[nt], zero, 0, 0, 0);
  }
  __syncthreads();   // gis B-reads complete before zeroing

  for (int i = tid; i < 2 * NB * 104 / 2; i += 256) ((unsigned int*)z)[i] = 0;
  #pragma unroll
  for (int reg = 0; reg < 4; reg++) {
    int j = 16 * w + 4 * q + reg;
    float br = bih[j] + bhh[j];
    float bz = bih[64 + j] + bhh[64 + j];
    float bn = bih[128 + j];
    #pragma unroll
    for (int nt = 0; nt < 2; nt++) {
      gis[0][nt][reg] += br;
      gis[1][nt][reg] += bz;
      gis[2][nt][reg] += bn;
    }
  }
  __syncthreads();

  float hreg[2][4] = {{0, 0, 0, 0}, {0, 0, 0, 0}};

  // prefetch xd(0)
  float4 xv = make_float4(0.f, 0.f, 0.f, 0.f);
  if (tid < 64) xv = *(const float4*)(xdyn + (size_t)n0 * 8 + tid * 4);

  for (int t = 0; t < T; t++) {
    const int b = t & 1;
    // stage xd(t) into z[b] cols 64..72; prefetch xd(t+1)
    if (tid < 64) {
      unsigned long long pk =
          (unsigned long long)f2bf(xv.x) |
          ((unsigned long long)f2bf(xv.y) << 16) |
          ((unsigned long long)f2bf(xv.z) << 32) |
          ((unsigned long long)f2bf(xv.w) << 48);
      *(unsigned long long*)&z[b][tid >> 1][64 + (tid & 1) * 4] = pk;
      if (t + 1 < T)
        xv = *(const float4*)(xdyn + ((size_t)(t + 1) * N + n0) * 8 + tid * 4);
    }
    __syncthreads();   // S1 (the ONLY barrier per step): xd(t), h_{t-1}, s_red(t-1) all visible

    // reduce + output for step t-2 (partials written during step t-1 into s_red[1-b])
    if (t >= 2 && tid < 32) {
      float s = s_red[1 - b][tid][0] + s_red[1 - b][tid][1] +
                s_red[1 - b][tid][2] + s_red[1 - b][tid][3];
      out[(size_t)(t - 2) * N + n0 + tid] = sigmoidf_(s + h2b0);
    }

    #pragma unroll
    for (int nt = 0; nt < 2; nt++) {
      bf16x8_t B0 = *(const bf16x8_t*)&z[b][nt * 16 + ml][q * 8];
      bf16x8_t B1 = *(const bf16x8_t*)&z[b][nt * 16 + ml][32 + q * 8];
      bf16x8_t B2 = *(const bf16x8_t*)&z[b][nt * 16 + ml][64 + q * 8];

      // main GEMM (gates for step t)
      f32x4_t ar = {0.f, 0.f, 0.f, 0.f}, az = ar, ain = ar, ahn = ar;
      ar  = __builtin_amdgcn_mfma_f32_16x16x32_bf16(A_r[0], B0, ar, 0, 0, 0);
      az  = __builtin_amdgcn_mfma_f32_16x16x32_bf16(A_z[0], B0, az, 0, 0, 0);
      ahn = __builtin_amdgcn_mfma_f32_16x16x32_bf16(A_hn[0], B0, ahn, 0, 0, 0);
      ar  = __builtin_amdgcn_mfma_f32_16x16x32_bf16(A_r[1], B1, ar, 0, 0, 0);
      az  = __builtin_amdgcn_mfma_f32_16x16x32_bf16(A_z[1], B1, az, 0, 0, 0);
      ahn = __builtin_amdgcn_mfma_f32_16x16x32_bf16(A_hn[1], B1, ahn, 0, 0, 0);
      ar  = __builtin_amdgcn_mfma_f32_16x16x32_bf16(A_r[2], B2, ar, 0, 0, 0);
      az  = __builtin_amdgcn_mfma_f32_16x16x32_bf16(A_z[2], B2, az, 0, 0, 0);
      ain = __builtin_amdgcn_mfma_f32_16x16x32_bf16(A_in,  B2, ain, 0, 0, 0);

      // head GEMM for step t-1: B0/B1 ARE h_{t-1} — no extra LDS reads
      if (t >= 1) {
        f32x4_t ha = {0.f, 0.f, 0.f, 0.f};
        ha = __builtin_amdgcn_mfma_f32_16x16x32_bf16(Ah[0], B0, ha, 0, 0, 0);
        ha = __builtin_amdgcn_mfma_f32_16x16x32_bf16(Ah[1], B1, ha, 0, 0, 0);
        float p = 0.0f;
        #pragma unroll
        for (int reg = 0; reg < 4; reg++)
          p += h2w_r[reg] * fmaxf(ha[reg] + h1b_r[reg], 0.0f);
        p += __shfl_xor(p, 16, 64);
        p += __shfl_xor(p, 32, 64);
        if (q == 0) s_red[b][nt * 16 + ml][w] = p;
      }

      // epilogue: gates + state update; h_t -> the OTHER buffer
      unsigned short hb[4];
      #pragma unroll
      for (int reg = 0; reg < 4; reg++) {
        float r  = sigmoidf_(gis[0][nt][reg] + ar[reg]);
        float zg = sigmoidf_(gis[1][nt][reg] + az[reg]);
        float hn = bhh_n[reg] + ahn[reg];
        float nn = tanhf_(gis[2][nt][reg] + ain[reg] + r * hn);
        float h  = fmaf(zg, hreg[nt][reg] - nn, nn);
        hreg[nt][reg] = h;
        hb[reg] = f2bf(h);
      }
      unsigned long long pk =
          (unsigned long long)hb[0] | ((unsigned long long)hb[1] << 16) |
          ((unsigned long long)hb[2] << 32) | ((unsigned long long)hb[3] << 48);
      *(unsigned long long*)&z[1 - b][nt * 16 + ml][16 * w + 4 * q] = pk;
    }
  }

  // ---- drain: head(T-1), out(T-2), out(T-1) ----
  const int bl = (T - 1) & 1;          // last loop buffer
  __syncthreads();                     // h_{T-1} in z[1-bl]; s_red[bl] holds head(T-2)

  if (tid < 32) {
    float s = s_red[bl][tid][0] + s_red[bl][tid][1] +
              s_red[bl][tid][2] + s_red[bl][tid][3];
    out[(size_t)(T - 2) * N + n0 + tid] = sigmoidf_(s + h2b0);
  }
  #pragma unroll
  for (int nt = 0; nt < 2; nt++) {
    bf16x8_t B0 = *(const bf16x8_t*)&z[1 - bl][nt * 16 + ml][q * 8];
    bf16x8_t B1 = *(const bf16x8_t*)&z[1 - bl][nt * 16 + ml][32 + q * 8];
    f32x4_t ha = {0.f, 0.f, 0.f, 0.f};
    ha = __builtin_amdgcn_mfma_f32_16x16x32_bf16(Ah[0], B0, ha, 0, 0, 0);
    ha = __builtin_amdgcn_mfma_f32_16x16x32_bf16(Ah[1], B1, ha, 0, 0, 0);
    float p = 0.0f;
    #pragma unroll
    for (int reg = 0; reg < 4; reg++)
      p += h2w_r[reg] * fmaxf(ha[reg] + h1b_r[reg], 0.0f);
    p += __shfl_xor(p, 16, 64);
    p += __shfl_xor(p, 32, 64);
    if (q == 0) s_red[1 - bl][nt * 16 + ml][w] = p;
  }
  __syncthreads();
  if (tid < 32) {
    float s = s_red[1 - bl][tid][0] + s_red[1 - bl][tid][1] +
              s_red[1 - bl][tid][2] + s_red[1 - bl][tid][3];
    out[(size_t)(T - 1) * N + n0 + tid] = sigmoidf_(s + h2b0);
  }
}

extern "C" void kernel_launch(void* const* d_in, const int* in_sizes, int n_in,
                              void* d_out, int out_size, void* d_ws, size_t ws_size,
                              hipStream_t stream) {
  const float* Xs   = (const float*)d_in[0];
  const float* Xd   = (const float*)d_in[1];
  const int*   erow = (const int*)d_in[2];
  const int*   ecol = (const int*)d_in[3];
  const float* evl  = (const float*)d_in[4];
  const float* g1W  = (const float*)d_in[5];
  const float* g1b  = (const float*)d_in[6];
  const float* g2W  = (const float*)d_in[7];
  const float* g2b  = (const float*)d_in[8];
  const float* Wih  = (const float*)d_in[9];
  const float* Whh  = (const float*)d_in[10];
  const float* bih  = (const float*)d_in[11];
  const float* bhh  = (const float*)d_in[12];
  const float* h1W  = (const float*)d_in[13];
  const float* h1b  = (const float*)d_in[14];
  const float* h2W  = (const float*)d_in[15];
  const float* h2b  = (const float*)d_in[16];

  const int N = in_sizes[0] / 32;
  const int E = in_sizes[2];
  const int T = in_sizes[1] / (N * 8);

  float* out  = (float*)d_out;
  char*  base = (char*)d_ws;
  float* buf0 = (float*)base;                     // N*32 f32 (also aliased as bf16)
  float* buf1 = buf0 + (size_t)N * 32;            // N*32 f32
  int*   cnt    = (int*)(buf1 + (size_t)N * 32);  // N
  int*   startv = cnt + N;                        // N
  int*   cursor = startv + N;                     // N
  int*   bsum   = cursor + N;                     // 512
  int*   bsumx  = bsum + 512;                     // 512
  int2*  pairs  = (int2*)(bsumx + 512);           // E
  unsigned short* buf0h = (unsigned short*)buf0;  // bf16 view of buf0

  const size_t needed = (size_t)((char*)(pairs + E) - base);
  const bool use_csr = (ws_size >= needed);

  const int linBlocks = (N + 7) / 8;
  const int eBlocks   = (E + 255) / 256;
  const int nb1       = (N + 255) / 256;

  if (use_csr) {
    // GraphConv 1 linear -> bf16
    lin32_kernel<false, true><<<linBlocks, 256, 0, stream>>>(Xs, g1W, g1b, buf0h, N);

    // build CSR once
    hipMemsetAsync(cnt, 0, (size_t)N * sizeof(int), stream);
    hist_k<<<eBlocks, 256, 0, stream>>>(erow, cnt, E);
    scan1_k<<<nb1, 256, 0, stream>>>(cnt, startv, bsum, N);
    scan2_k<<<1, 512, 0, stream>>>(bsum, bsumx, nb1);
    scan3_k<<<nb1, 256, 0, stream>>>(startv, bsumx, cursor, N);
    scatter_k<<<eBlocks, 256, 0, stream>>>(erow, ecol, evl, cursor, pairs, E);

    spmm_csr_bf16_k<<<(N + 3) / 4, 256, 0, stream>>>(startv, cnt, pairs, buf0h, buf1, N);
    lin32_kernel<true, true><<<linBlocks, 256, 0, stream>>>(buf1, g2W, g2b, buf0h, N);
    spmm_csr_bf16_k<<<(N + 3) / 4, 256, 0, stream>>>(startv, cnt, pairs, buf0h, buf1, N);
  } else {
    lin32_kernel<false, false><<<linBlocks, 256, 0, stream>>>(Xs, g1W, g1b, buf0, N);
    const int spmmBlocks = (int)(((long)E * 8 + 255) / 256);
    hipMemsetAsync(buf1, 0, (size_t)N * 32 * sizeof(float), stream);
    spmm_kernel<<<spmmBlocks, 256, 0, stream>>>(erow, ecol, evl, buf0, buf1, E);
    lin32_kernel<true, false><<<linBlocks, 256, 0, stream>>>(buf1, g2W, g2b, buf0, N);
    hipMemsetAsync(buf1, 0, (size_t)N * 32 * sizeof(float), stream);
    spmm_kernel<<<spmmBlocks, 256, 0, stream>>>(erow, ecol, evl, buf0, buf1, E);
  }

  // fused MFMA GRU + head
  gru_head_mfma<<<N / NB, 256, 0, stream>>>(buf1, Xd, Wih, Whh, bih, bhh,
                                            h1W, h1b, h2W, h2b, out, N, T);
}